// Round 1
// baseline (1429.855 us; speedup 1.0000x reference)
//
#include <hip/hip_runtime.h>
#include <stdint.h>

typedef unsigned short u16;   // raw bf16 bits

#define NB   4
#define NC   512
#define NC8  64
#define NH   128
#define NW   128
#define NHW  16384

__device__ __forceinline__ float b2f(u16 u) {
  union { float f; uint32_t i; } x; x.i = ((uint32_t)u) << 16; return x.f;
}
__device__ __forceinline__ u16 f2b(float f) {
  union { float f; uint32_t u; } x; x.f = f;
  uint32_t r = x.u + 0x7FFF + ((x.u >> 16) & 1);
  return (u16)(r >> 16);
}
__device__ __forceinline__ void load8bf(const u16* __restrict__ p, float* f) {
  uint4 u = *reinterpret_cast<const uint4*>(p);
  f[0] = b2f((u16)(u.x & 0xFFFF)); f[1] = b2f((u16)(u.x >> 16));
  f[2] = b2f((u16)(u.y & 0xFFFF)); f[3] = b2f((u16)(u.y >> 16));
  f[4] = b2f((u16)(u.z & 0xFFFF)); f[5] = b2f((u16)(u.z >> 16));
  f[6] = b2f((u16)(u.w & 0xFFFF)); f[7] = b2f((u16)(u.w >> 16));
}
__device__ __forceinline__ uint4 pack8bf(const float* f) {
  uint4 u;
  u.x = (uint32_t)f2b(f[0]) | ((uint32_t)f2b(f[1]) << 16);
  u.y = (uint32_t)f2b(f[2]) | ((uint32_t)f2b(f[3]) << 16);
  u.z = (uint32_t)f2b(f[4]) | ((uint32_t)f2b(f[5]) << 16);
  u.w = (uint32_t)f2b(f[6]) | ((uint32_t)f2b(f[7]) << 16);
  return u;
}

// ---------------------------------------------------------------------------
// K1: 64-channel projection (q or k):  y[b,o,hw] = sum_c W[o,c] x[b,c,hw] + bias[o]
// grid (hw_tiles=128, b=4), block 256.  hw tile = 128 (one h row).
__global__ __launch_bounds__(256) void proj64(const float* __restrict__ x,
                                              const float* __restrict__ Wt,
                                              const float* __restrict__ bias,
                                              u16* __restrict__ y) {
  int b = blockIdx.y;
  int hw0 = blockIdx.x * 128;
  __shared__ float xs[32][128];   // [cc][w]
  __shared__ float ws[64][32];    // [o][cc]
  int t = threadIdx.x;
  int og = t >> 5;      // 0..7  (8 o per group)
  int wl = t & 31;      // 0..31 (4 w each)
  float acc[8][4];
  for (int i = 0; i < 8; i++) for (int j = 0; j < 4; j++) acc[i][j] = 0.f;
  const float* xb = x + (size_t)b * NC * NHW + hw0;
  for (int c0 = 0; c0 < NC; c0 += 32) {
    for (int i = 0; i < 4; i++) {                 // 1024 float4 loads of x
      int idx4 = t + i * 256;
      int cc = idx4 >> 5, w4 = (idx4 & 31) * 4;
      float4 v = *reinterpret_cast<const float4*>(&xb[(size_t)(c0 + cc) * NHW + w4]);
      xs[cc][w4 + 0] = v.x; xs[cc][w4 + 1] = v.y; xs[cc][w4 + 2] = v.z; xs[cc][w4 + 3] = v.w;
    }
    for (int i = 0; i < 2; i++) {                 // 512 float4 loads of W
      int idx4 = t + i * 256;
      int o = idx4 >> 3, cb4 = (idx4 & 7) * 4;
      float4 v = *reinterpret_cast<const float4*>(&Wt[(size_t)o * NC + c0 + cb4]);
      ws[o][cb4 + 0] = v.x; ws[o][cb4 + 1] = v.y; ws[o][cb4 + 2] = v.z; ws[o][cb4 + 3] = v.w;
    }
    __syncthreads();
    for (int cc = 0; cc < 32; cc++) {
      float a[8], bb[4];
      for (int i = 0; i < 8; i++) a[i] = ws[og * 8 + i][cc];
      for (int j = 0; j < 4; j++) bb[j] = xs[cc][wl * 4 + j];
      for (int i = 0; i < 8; i++)
        for (int j = 0; j < 4; j++) acc[i][j] += a[i] * bb[j];
    }
    __syncthreads();
  }
  for (int i = 0; i < 8; i++) {
    int o = og * 8 + i;
    float bv = bias[o];
    u16 tmp[4];
    for (int j = 0; j < 4; j++) tmp[j] = f2b(acc[i][j] + bv);
    uint2 pk;
    pk.x = (uint32_t)tmp[0] | ((uint32_t)tmp[1] << 16);
    pk.y = (uint32_t)tmp[2] | ((uint32_t)tmp[3] << 16);
    *reinterpret_cast<uint2*>(&y[(size_t)(b * NC8 + o) * NHW + hw0 + wl * 4]) = pk;
  }
}

// ---------------------------------------------------------------------------
// K2: 512-channel projection (v). grid (hw_tiles=128, o_tiles=4, b=4), block 256.
__global__ __launch_bounds__(256) void proj_v(const float* __restrict__ x,
                                              const float* __restrict__ Wt,
                                              const float* __restrict__ bias,
                                              u16* __restrict__ y) {
  int b = blockIdx.z;
  int o0 = blockIdx.y * 128;
  int hw0 = blockIdx.x * 128;
  __shared__ float as_[128][17];  // [o][cc]  (+1 pad)
  __shared__ float xs[16][128];   // [cc][w]
  int t = threadIdx.x;
  int ty = t >> 4, tx = t & 15;
  float acc[8][8];
  for (int i = 0; i < 8; i++) for (int j = 0; j < 8; j++) acc[i][j] = 0.f;
  const float* xb = x + (size_t)b * NC * NHW + hw0;
  for (int c0 = 0; c0 < NC; c0 += 16) {
    {
      int o = t >> 1, ccb = (t & 1) * 8;
      const float* wp = &Wt[(size_t)(o0 + o) * NC + c0 + ccb];
      for (int i = 0; i < 8; i++) as_[o][ccb + i] = wp[i];
    }
    for (int i = 0; i < 2; i++) {
      int idx4 = t + i * 256;
      int cc = idx4 >> 5, w4 = (idx4 & 31) * 4;
      float4 v = *reinterpret_cast<const float4*>(&xb[(size_t)(c0 + cc) * NHW + w4]);
      xs[cc][w4 + 0] = v.x; xs[cc][w4 + 1] = v.y; xs[cc][w4 + 2] = v.z; xs[cc][w4 + 3] = v.w;
    }
    __syncthreads();
    for (int cc = 0; cc < 16; cc++) {
      float a[8], bb[8];
      for (int i = 0; i < 8; i++) a[i] = as_[ty * 8 + i][cc];
      for (int j = 0; j < 8; j++) bb[j] = xs[cc][tx * 8 + j];
      for (int i = 0; i < 8; i++)
        for (int j = 0; j < 8; j++) acc[i][j] += a[i] * bb[j];
    }
    __syncthreads();
  }
  for (int i = 0; i < 8; i++) {
    int o = o0 + ty * 8 + i;
    float bv = bias[o];
    float row[8];
    for (int j = 0; j < 8; j++) row[j] = acc[i][j] + bv;
    *reinterpret_cast<uint4*>(&y[(size_t)(b * NC + o) * NHW + hw0 + tx * 8]) = pack8bf(row);
  }
}

// ---------------------------------------------------------------------------
// K3: transpose last two dims of (planes,128,128) bf16 tensor
__global__ __launch_bounds__(256) void transpose128(const u16* __restrict__ src,
                                                    u16* __restrict__ dst) {
  __shared__ u16 tile[32][33];
  int p = blockIdx.z;
  int i0 = blockIdx.y * 32, j0 = blockIdx.x * 32;
  int tx = threadIdx.x & 31, ty = threadIdx.x >> 5;
  const u16* s = src + (size_t)p * NHW;
  u16* d = dst + (size_t)p * NHW;
  for (int k = 0; k < 4; k++) {
    int i = i0 + ty + k * 8;
    tile[ty + k * 8][tx] = s[(size_t)i * 128 + j0 + tx];
  }
  __syncthreads();
  for (int k = 0; k < 4; k++) {
    int j = j0 + ty + k * 8;
    d[(size_t)j * 128 + i0 + tx] = tile[tx][ty + k * 8];
  }
}

// ---------------------------------------------------------------------------
// K4: energy. For isH=0 (energy_W): block (s=h, b): e[w][j] = sum_c q[b,c,h,w] k[b,c,h,j]
//     For isH=1 (energy_H): pass q_sw,k_sw, s=w: e[h][j] = sum_c q[b,c,h,w] k[b,c,j,w], mask j==h
// att layout (B,H,W,256): [0:128)=eH, [128:256)=eW
__global__ __launch_bounds__(256) void energy_kern(const u16* __restrict__ Q,
                                                   const u16* __restrict__ K,
                                                   u16* __restrict__ att, int isH) {
  int b = blockIdx.y, s = blockIdx.x;
  __shared__ float qs[64][128];
  __shared__ float ks[64][128];
  int t = threadIdx.x;
  const u16* Qb = Q + (size_t)b * NC8 * NHW + s * 128;
  const u16* Kb = K + (size_t)b * NC8 * NHW + s * 128;
  for (int i = 0; i < 4; i++) {        // 8192 elems each, 8 at a time
    int idx8 = t + i * 256;
    int c = idx8 >> 4, x8 = (idx8 & 15) * 8;
    float f[8];
    load8bf(&Qb[(size_t)c * NHW + x8], f);
    for (int j = 0; j < 8; j++) qs[c][x8 + j] = f[j];
    load8bf(&Kb[(size_t)c * NHW + x8], f);
    for (int j = 0; j < 8; j++) ks[c][x8 + j] = f[j];
  }
  __syncthreads();
  int ty = t >> 4, tx = t & 15;
  float acc[8][8];
  for (int i = 0; i < 8; i++) for (int j = 0; j < 8; j++) acc[i][j] = 0.f;
  for (int c = 0; c < 64; c++) {
    float a[8], bb[8];
    for (int i = 0; i < 8; i++) a[i] = qs[c][ty * 8 + i];
    for (int j = 0; j < 8; j++) bb[j] = ks[c][tx * 8 + j];
    for (int i = 0; i < 8; i++)
      for (int j = 0; j < 8; j++) acc[i][j] += a[i] * bb[j];
  }
  size_t attb = (size_t)b * 4194304;
  for (int i = 0; i < 8; i++) {
    int r = ty * 8 + i;
    float row[8];
    for (int j = 0; j < 8; j++) {
      int jj = tx * 8 + j;
      float v = acc[i][j];
      if (isH && jj == r) v = -1e30f;
      row[j] = v;
    }
    size_t addr;
    if (isH) addr = attb + (size_t)r * 32768 + (size_t)s * 256 + tx * 8;
    else     addr = attb + (size_t)s * 32768 + (size_t)r * 256 + 128 + tx * 8;
    *reinterpret_cast<uint4*>(&att[addr]) = pack8bf(row);
  }
}

// ---------------------------------------------------------------------------
// K5: softmax over 256-entry rows, in place. One wave per row.
__global__ __launch_bounds__(256) void softmax_kern(u16* __restrict__ att) {
  int wave = threadIdx.x >> 6;
  int lane = threadIdx.x & 63;
  size_t row = (size_t)blockIdx.x * 4 + wave;
  u16* p = att + row * 256;
  uint2 u = *reinterpret_cast<const uint2*>(&p[lane * 4]);
  float v[4];
  v[0] = b2f((u16)(u.x & 0xFFFF)); v[1] = b2f((u16)(u.x >> 16));
  v[2] = b2f((u16)(u.y & 0xFFFF)); v[3] = b2f((u16)(u.y >> 16));
  float mx = fmaxf(fmaxf(v[0], v[1]), fmaxf(v[2], v[3]));
  for (int off = 32; off; off >>= 1) mx = fmaxf(mx, __shfl_xor(mx, off));
  float sum = 0.f;
  for (int i = 0; i < 4; i++) { v[i] = __expf(v[i] - mx); sum += v[i]; }
  for (int off = 32; off; off >>= 1) sum += __shfl_xor(sum, off);
  float inv = 1.f / sum;
  uint2 o;
  o.x = (uint32_t)f2b(v[0] * inv) | ((uint32_t)f2b(v[1] * inv) << 16);
  o.y = (uint32_t)f2b(v[2] * inv) | ((uint32_t)f2b(v[3] * inv) << 16);
  *reinterpret_cast<uint2*>(&p[lane * 4]) = o;
}

// ---------------------------------------------------------------------------
// K6: output GEMM.  block (ct, s, b): out[c][r] = sum_j V[b, ct*128+c, s*128+j] * Batt[r][j]
//   isH=0 (out_W): V=v natural, s=h, r=w, Batt row = att[b,s,r,128+j], out[b,c,h=s,w=r]
//   isH=1 (out_H): V=v_sw,      s=w, r=h, Batt row = att[b,r,s,j],     out_sw[b,c,w=s,h=r]
// out addr = b*8388608 + c_glob*16384 + s*128 + r   (same form both cases)
template <typename OT>
__global__ __launch_bounds__(256) void out_gemm(const u16* __restrict__ V,
                                                const u16* __restrict__ att,
                                                OT* __restrict__ out, int isH) {
  int ct = blockIdx.x, s = blockIdx.y, b = blockIdx.z;
  __shared__ float vs[128][17];
  __shared__ float bs[128][17];
  int t = threadIdx.x;
  int ty = t >> 4, tx = t & 15;
  float acc[8][8];
  for (int i = 0; i < 8; i++) for (int j = 0; j < 8; j++) acc[i][j] = 0.f;
  size_t attb = (size_t)b * 4194304;
  int rr = t >> 1, jb = (t & 1) * 8;
  const u16* vp = V + (size_t)(b * NC + ct * 128 + rr) * NHW + s * 128 + jb;
  for (int j0 = 0; j0 < 128; j0 += 16) {
    float f[8];
    load8bf(vp + j0, f);
    for (int i = 0; i < 8; i++) vs[rr][jb + i] = f[i];
    size_t arow = attb + (isH ? ((size_t)rr * 32768 + (size_t)s * 256)
                              : ((size_t)s * 32768 + (size_t)rr * 256 + 128)) + j0 + jb;
    load8bf(&att[arow], f);
    for (int i = 0; i < 8; i++) bs[rr][jb + i] = f[i];
    __syncthreads();
    for (int jj = 0; jj < 16; jj++) {
      float a[8], bb[8];
      for (int i = 0; i < 8; i++) a[i] = vs[ty * 8 + i][jj];
      for (int j = 0; j < 8; j++) bb[j] = bs[tx * 8 + j][jj];
      for (int i = 0; i < 8; i++)
        for (int j = 0; j < 8; j++) acc[i][j] += a[i] * bb[j];
    }
    __syncthreads();
  }
  for (int i = 0; i < 8; i++) {
    int c = ct * 128 + ty * 8 + i;
    size_t base = (size_t)b * 8388608 + (size_t)c * NHW + (size_t)s * 128 + tx * 8;
    for (int j = 0; j < 8; j++) {
      float v = acc[i][j];
      if constexpr (sizeof(OT) == 2) out[base + j] = f2b(v);
      else                           out[base + j] = v;
    }
  }
}

// ---------------------------------------------------------------------------
// K7: epilogue. out0 = g1*(outW + outH^T + 2) + xe ; out1 = g2*(...) + xq
// outW aliases out0 (same-index read then write by same thread -> safe).
__global__ __launch_bounds__(256) void epilogue(const float* outW,
                                                const u16* __restrict__ outHsw,
                                                const float* __restrict__ xe,
                                                const float* __restrict__ xq,
                                                const float* __restrict__ g1p,
                                                const float* __restrict__ g2p,
                                                float* out0, float* out1) {
  __shared__ float tile[32][33];
  int p = blockIdx.z;                 // b*512 + c
  int h0 = blockIdx.y * 32, w0 = blockIdx.x * 32;
  int tx = threadIdx.x & 31, ty = threadIdx.x >> 5;
  const u16* src = outHsw + (size_t)p * NHW;   // [w][h]
  for (int k = 0; k < 4; k++) {
    int w = w0 + ty + k * 8;
    tile[ty + k * 8][tx] = b2f(src[(size_t)w * 128 + h0 + tx]);
  }
  __syncthreads();
  float g1 = g1p[0], g2 = g2p[0];
  for (int k = 0; k < 4; k++) {
    int h = h0 + ty + k * 8;
    size_t idx = (size_t)p * NHW + (size_t)h * 128 + w0 + tx;
    float sum = outW[idx] + tile[tx][ty + k * 8] + 2.0f;
    out0[idx] = g1 * sum + xe[idx];
    out1[idx] = g2 * sum + xq[idx];
  }
}

// ---------------------------------------------------------------------------
extern "C" void kernel_launch(void* const* d_in, const int* in_sizes, int n_in,
                              void* d_out, int out_size, void* d_ws, size_t ws_size,
                              hipStream_t stream) {
  (void)in_sizes; (void)n_in; (void)out_size; (void)ws_size;
  const float* xe = (const float*)d_in[0];
  const float* xq = (const float*)d_in[1];
  const float* Wq = (const float*)d_in[2];
  const float* bq = (const float*)d_in[3];
  const float* Wk = (const float*)d_in[4];
  const float* bk = (const float*)d_in[5];
  const float* Wv = (const float*)d_in[6];
  const float* bv = (const float*)d_in[7];
  const float* g1 = (const float*)d_in[8];
  const float* g2 = (const float*)d_in[9];
  float* out = (float*)d_out;

  char* ws = (char*)d_ws;
  u16* q_n    = (u16*)(ws + 0);            //  8 MiB  (4,64,128,128)
  u16* k_n    = (u16*)(ws + 8388608);      //  8 MiB
  u16* q_sw   = (u16*)(ws + 16777216);     //  8 MiB  (b,c,w,h)
  u16* k_sw   = (u16*)(ws + 25165824);     //  8 MiB
  u16* v_n    = (u16*)(ws + 33554432);     // 64 MiB  (4,512,128,128)
  u16* v_sw   = (u16*)(ws + 100663296);    // 64 MiB
  u16* att    = (u16*)(ws + 167772160);    // 32 MiB  (4,128,128,256)
  u16* outHsw = (u16*)(ws + 201326592);    // 64 MiB  (b,c,w,h)

  proj64<<<dim3(128, 4), 256, 0, stream>>>(xq, Wq, bq, q_n);
  proj64<<<dim3(128, 4), 256, 0, stream>>>(xe, Wk, bk, k_n);
  proj_v<<<dim3(128, 4, 4), 256, 0, stream>>>(xe, Wv, bv, v_n);
  transpose128<<<dim3(4, 4, 256), 256, 0, stream>>>(q_n, q_sw);
  transpose128<<<dim3(4, 4, 256), 256, 0, stream>>>(k_n, k_sw);
  transpose128<<<dim3(4, 4, 2048), 256, 0, stream>>>(v_n, v_sw);
  energy_kern<<<dim3(128, 4), 256, 0, stream>>>(q_n, k_n, att, 0);
  energy_kern<<<dim3(128, 4), 256, 0, stream>>>(q_sw, k_sw, att, 1);
  softmax_kern<<<dim3(16384), 256, 0, stream>>>(att);
  out_gemm<float><<<dim3(4, 128, 4), 256, 0, stream>>>(v_n, att, out, 0);
  out_gemm<u16><<<dim3(4, 128, 4), 256, 0, stream>>>(v_sw, att, outHsw, 1);
  epilogue<<<dim3(4, 4, 2048), 256, 0, stream>>>(out, outHsw, xe, xq, g1, g2,
                                                 out, out + 33554432);
}